// Round 1
// baseline (302.244 us; speedup 1.0000x reference)
//
#include <hip/hip_runtime.h>
#include <hip/hip_bf16.h>

// Problem constants (from reference setup_inputs)
#define N_NODES 10000
#define N_EDGES 320000
#define DIM_D   128
#define DIM_H   256

// Output layout (flat f32 concat, element offsets):
//   z  : [0,           2,560,000)
//   z1 : [2,560,000,   5,120,000)
//   z2 : [5,120,000,   7,680,000)
//   rw1: [7,680,000,   107,680,000)
//   rw2: [107,680,000, 207,680,000)
#define Z_ELEMS   (N_NODES * DIM_H)          // 2,560,000
#define RW_ELEMS  ((size_t)N_NODES * N_NODES) // 100,000,000
#define OFF_Z1    ((size_t)Z_ELEMS)
#define OFF_Z2    ((size_t)2 * Z_ELEMS)
#define OFF_RW1   ((size_t)3 * Z_ELEMS)
#define OFF_RW2   (OFF_RW1 + RW_ELEMS)

// --- rowsum[j] = sum of edge weights with source j ---------------------------
__global__ void rowsum_kernel(const int* __restrict__ ei,
                              const float* __restrict__ ew,
                              float* __restrict__ rowsum, int E) {
    int e = blockIdx.x * blockDim.x + threadIdx.x;
    if (e >= E) return;
    atomicAdd(&rowsum[ei[e]], ew[e]);   // ei[e] = edge_index[0][e] (source)
}

// --- scatter normalized edges into both rw1 and rw2 --------------------------
// rw[s,d] += w / (rowsum[d] + 1e-20)   (divisor indexed by COLUMN d, per the
// reference's broadcast of adj.sum(axis=1) over the last axis)
__global__ void scatter_kernel(const int* __restrict__ ei,
                               const float* __restrict__ ew,
                               const float* __restrict__ rowsum,
                               float* __restrict__ rw1,
                               float* __restrict__ rw2, int E, int N) {
    int e = blockIdx.x * blockDim.x + threadIdx.x;
    if (e >= E) return;
    int s = ei[e];
    int d = ei[E + e];
    float v = ew[e] / (rowsum[d] + 1e-20f);
    size_t off = (size_t)s * N + d;
    atomicAdd(&rw1[off], v);
    atomicAdd(&rw2[off], v);
}

// --- z = x @ W_enc, written to z, z1, z2 ------------------------------------
// One thread computes 4 output columns (float4 accumulate), W loads coalesced.
__global__ void gemm_kernel(const float* __restrict__ x,
                            const float* __restrict__ W,
                            float* __restrict__ out) {
    int idx = blockIdx.x * blockDim.x + threadIdx.x;   // N * H/4 threads
    int row = idx >> 6;            // H/4 = 64 col-groups per row
    int h4  = (idx & 63) << 2;
    if (row >= N_NODES) return;

    const float* xr = x + (size_t)row * DIM_D;
    float4 acc = make_float4(0.f, 0.f, 0.f, 0.f);
#pragma unroll 8
    for (int k = 0; k < DIM_D; ++k) {
        float xv = xr[k];
        float4 w = *reinterpret_cast<const float4*>(W + (size_t)k * DIM_H + h4);
        acc.x += xv * w.x;
        acc.y += xv * w.y;
        acc.z += xv * w.z;
        acc.w += xv * w.w;
    }
    size_t o = (size_t)row * DIM_H + h4;
    *reinterpret_cast<float4*>(out + o)          = acc;
    *reinterpret_cast<float4*>(out + OFF_Z1 + o) = acc;
    *reinterpret_cast<float4*>(out + OFF_Z2 + o) = acc;
}

extern "C" void kernel_launch(void* const* d_in, const int* in_sizes, int n_in,
                              void* d_out, int out_size, void* d_ws, size_t ws_size,
                              hipStream_t stream) {
    const float* x      = (const float*)d_in[0];
    const int*   ei     = (const int*)d_in[1];    // (2,E) row-major: [0..E)=src, [E..2E)=dst
    const float* ew     = (const float*)d_in[2];
    const float* W_enc  = (const float*)d_in[3];
    float* out = (float*)d_out;

    float* rowsum = (float*)d_ws;                 // N_NODES floats (40 KB)

    // 1) zero rowsum scratch (must be re-zeroed every call: determinism)
    hipMemsetAsync(rowsum, 0, N_NODES * sizeof(float), stream);

    // 2) zero both rw regions (contiguous 800 MB) — the adjacency is sparse,
    //    so zero + scatter avoids ever reading a dense matrix back.
    hipMemsetAsync(out + OFF_RW1, 0, 2 * RW_ELEMS * sizeof(float), stream);

    // 3) rowsum[j] = sum of outgoing edge weights of node j
    rowsum_kernel<<<(N_EDGES + 255) / 256, 256, 0, stream>>>(ei, ew, rowsum, N_EDGES);

    // 4) scatter normalized weights into rw1 and rw2
    scatter_kernel<<<(N_EDGES + 255) / 256, 256, 0, stream>>>(
        ei, ew, rowsum, out + OFF_RW1, out + OFF_RW2, N_EDGES, N_NODES);

    // 5) z = x @ W_enc  -> z, z1, z2
    int gthreads = N_NODES * (DIM_H / 4);         // 640,000
    gemm_kernel<<<(gthreads + 255) / 256, 256, 0, stream>>>(x, W_enc, out);
}